// Round 1
// baseline (2076.509 us; speedup 1.0000x reference)
//
#include <hip/hip_runtime.h>
#include <math.h>

#define B_SZ 32768
#define D_SZ 1024
#define R_SZ 64
#define E_SZ 4
#define L_SZ 3
#define NC   256          // E*R
#define TR   64           // rows per block
#define NTHR 512          // 8 waves

typedef __attribute__((ext_vector_type(8))) short bf16x8;
typedef __attribute__((ext_vector_type(4))) float f32x4;

__device__ __forceinline__ short f2bf(float f) {
    union { float f; unsigned u; } c; c.f = f;
    unsigned r = c.u + 0x7fffu + ((c.u >> 16) & 1u);   // round-to-nearest-even
    return (short)(r >> 16);
}

// Vt[l][c][d] = bf16(V[l][e][d][r]), c = e*64+r   (B-operand for v1: k=d contiguous)
__global__ __launch_bounds__(256) void pack_vt(const float* __restrict__ V,
                                               short* __restrict__ Vt) {
    int idx = blockIdx.x * 256 + threadIdx.x;          // L*256*1024
    int d = idx & 1023;
    int c = (idx >> 10) & 255;
    int l = idx >> 18;
    int e = c >> 6, r = c & 63;
    Vt[idx] = f2bf(V[((size_t)(l * E_SZ + e) * D_SZ + d) * R_SZ + r]);
}
// Ub[l][d][c] = bf16(U[l][e][d][s]), c = e*64+s    (B-operand for uv: k=c contiguous)
__global__ __launch_bounds__(256) void pack_ub(const float* __restrict__ U,
                                               short* __restrict__ Ub) {
    int idx = blockIdx.x * 256 + threadIdx.x;          // L*1024*256
    int c = idx & 255;
    int d = (idx >> 8) & 1023;
    int l = idx >> 18;
    int e = c >> 6, s = c & 63;
    Ub[idx] = f2bf(U[((size_t)(l * E_SZ + e) * D_SZ + d) * R_SZ + s]);
}
// Ct[l][e][s][r] = bf16(C[l][e][r][s])             (B-operand for v2: k=r contiguous)
__global__ __launch_bounds__(256) void pack_ct(const float* __restrict__ C,
                                               short* __restrict__ Ct) {
    int idx = blockIdx.x * 256 + threadIdx.x;          // L*4*64*64
    int r = idx & 63;
    int s = (idx >> 6) & 63;
    int le = idx >> 12;
    Ct[idx] = f2bf(C[((size_t)le * R_SZ + r) * R_SZ + s]);
}

// All three cross layers fused. Row-wise dependency only, so each block loops
// over layers using `out` as its own inter-layer storage (block-local rows).
// Gating is fused into the staging pass (f32, precision-identical).
__global__ __launch_bounds__(NTHR, 4) void cross_fused(
    const float* __restrict__ x,           // x0 and layer-0 xi
    const float* __restrict__ G,
    const short* __restrict__ Vt, const short* __restrict__ Ub,
    const short* __restrict__ Ct, const float* __restrict__ bias,
    float* out)
{
    __shared__ short xsA[TR * 136];  // xi chunk, bf16, double-buffered (A)
    __shared__ short xsB[TR * 136];  // (B) — distinct arrays: provable no-alias
    __shared__ short wb[TR * 264];   // v1 then w, bf16, row stride 264
    __shared__ float ssc[TR * E_SZ]; // softmax scores

    const int t = threadIdx.x;
    const int b0 = blockIdx.x * TR;
    const int lane = t & 63;
    const int wv = t >> 6;           // wave 0..7
    const int m = lane & 15;         // A-row / B-col / C-col index
    const int q = lane >> 4;         // quad
    const int srow = t >> 3;         // staging: row
    const int sj = t & 7;            // staging: 16-float slice within 128-chunk

    #pragma unroll 1
    for (int l = 0; l < L_SZ; ++l) {
        const float* xi = (l == 0) ? x : out;
        const short* Vt_l = Vt + (size_t)l * NC * D_SZ;
        const short* Ub_l = Ub + (size_t)l * D_SZ * NC;
        const short* Ct_l = Ct + (size_t)l * E_SZ * R_SZ * R_SZ;
        const float* bias_l = bias + (size_t)l * D_SZ;

        // gating partials, accumulated during staging (f32)
        float g0 = 0.f, g1 = 0.f, g2 = 0.f, g3 = 0.f;

        // stage chunk kc (f32 global -> bf16 LDS) + gating partial accumulate
        auto stage = [&](int kc, short* xbuf) {
            const float4* src = (const float4*)(xi + (size_t)(b0 + srow) * D_SZ + kc * 128 + sj * 16);
            const float4* Gp  = (const float4*)(G + kc * 128 + sj * 16);
            short4* dst = (short4*)(xbuf + srow * 136 + sj * 16);
            #pragma unroll
            for (int p = 0; p < 4; ++p) {
                float4 v = src[p];
                float4 a0 = Gp[p];
                float4 a1 = Gp[p + 256];   // G row stride = D_SZ/4 float4
                float4 a2 = Gp[p + 512];
                float4 a3 = Gp[p + 768];
                g0 += v.x * a0.x + v.y * a0.y + v.z * a0.z + v.w * a0.w;
                g1 += v.x * a1.x + v.y * a1.y + v.z * a1.z + v.w * a1.w;
                g2 += v.x * a2.x + v.y * a2.y + v.z * a2.z + v.w * a2.w;
                g3 += v.x * a3.x + v.y * a3.y + v.z * a3.z + v.w * a3.w;
                short4 s;
                s.x = f2bf(v.x); s.y = f2bf(v.y); s.z = f2bf(v.z); s.w = f2bf(v.w);
                dst[p] = s;
            }
        };

        // ---------------- phase V: v1 = tanh(xi @ V), double-buffered ----------------
        f32x4 accV[4][2];
        #pragma unroll
        for (int rt = 0; rt < 4; ++rt)
            #pragma unroll
            for (int ct = 0; ct < 2; ++ct) accV[rt][ct] = (f32x4){0.f, 0.f, 0.f, 0.f};
        const int cbase = wv * 32;

        auto mfmaV = [&](int kc, const short* xbuf) {
            #pragma unroll
            for (int ks = 0; ks < 4; ++ks) {
                bf16x8 a[4];
                #pragma unroll
                for (int rt = 0; rt < 4; ++rt)
                    a[rt] = *(const bf16x8*)(xbuf + (rt * 16 + m) * 136 + ks * 32 + q * 8);
                #pragma unroll
                for (int ct = 0; ct < 2; ++ct) {
                    bf16x8 b = *(const bf16x8*)(Vt_l + (size_t)(cbase + ct * 16 + m) * D_SZ
                                                + kc * 128 + ks * 32 + q * 8);
                    #pragma unroll
                    for (int rt = 0; rt < 4; ++rt)
                        accV[rt][ct] = __builtin_amdgcn_mfma_f32_16x16x32_bf16(
                            a[rt], b, accV[rt][ct], 0, 0, 0);
                }
            }
        };

        stage(0, xsA);
        __syncthreads();
        #pragma unroll
        for (int kc2 = 0; kc2 < 4; ++kc2) {
            stage(2 * kc2 + 1, xsB);       // loads in flight while MFMAing xsA
            mfmaV(2 * kc2, xsA);
            __syncthreads();
            if (kc2 < 3) stage(2 * kc2 + 2, xsA);
            mfmaV(2 * kc2 + 1, xsB);
            __syncthreads();
        }

        // gating partials -> xsA overlay (xs dead now); v1 tanh -> wb
        {
            float* gf = (float*)xsA;
            gf[t * 4 + 0] = g0; gf[t * 4 + 1] = g1;
            gf[t * 4 + 2] = g2; gf[t * 4 + 3] = g3;
        }
        #pragma unroll
        for (int rt = 0; rt < 4; ++rt)
            #pragma unroll
            for (int ct = 0; ct < 2; ++ct)
                #pragma unroll
                for (int i = 0; i < 4; ++i) {
                    int row = rt * 16 + q * 4 + i;
                    int c = cbase + ct * 16 + m;
                    wb[row * 264 + c] = f2bf(tanhf(accV[rt][ct][i]));
                }
        __syncthreads();
        if (t < TR) {
            const float* gf = (const float*)xsA;
            float lg[E_SZ];
            #pragma unroll
            for (int e = 0; e < E_SZ; ++e) {
                float s = 0.f;
                #pragma unroll
                for (int jj = 0; jj < 8; ++jj) s += gf[(t * 8 + jj) * 4 + e];
                lg[e] = s;
            }
            float mx = fmaxf(fmaxf(lg[0], lg[1]), fmaxf(lg[2], lg[3]));
            float den = 0.f, ex[E_SZ];
            #pragma unroll
            for (int e = 0; e < E_SZ; ++e) { ex[e] = __expf(lg[e] - mx); den += ex[e]; }
            float inv = 1.f / den;
            #pragma unroll
            for (int e = 0; e < E_SZ; ++e) ssc[t * E_SZ + e] = ex[e] * inv;
        }
        __syncthreads();

        // ---------------- phase C: v2 = tanh(v1 @ C_e), w = v2*score ----------------
        {
            const int e = wv >> 1, rh = wv & 1;       // wave -> (expert, row-half)
            f32x4 accC[2][4];
            #pragma unroll
            for (int r2 = 0; r2 < 2; ++r2)
                #pragma unroll
                for (int st = 0; st < 4; ++st) accC[r2][st] = (f32x4){0.f, 0.f, 0.f, 0.f};
            #pragma unroll
            for (int ks = 0; ks < 2; ++ks) {
                bf16x8 a[2];
                #pragma unroll
                for (int r2 = 0; r2 < 2; ++r2) {
                    int rt = rh * 2 + r2;
                    a[r2] = *(const bf16x8*)(wb + (rt * 16 + m) * 264 + e * 64 + ks * 32 + q * 8);
                }
                #pragma unroll
                for (int st = 0; st < 4; ++st) {
                    bf16x8 b = *(const bf16x8*)(Ct_l + e * 4096 + (st * 16 + m) * 64 + ks * 32 + q * 8);
                    #pragma unroll
                    for (int r2 = 0; r2 < 2; ++r2)
                        accC[r2][st] = __builtin_amdgcn_mfma_f32_16x16x32_bf16(
                            a[r2], b, accC[r2][st], 0, 0, 0);
                }
            }
            #pragma unroll
            for (int r2 = 0; r2 < 2; ++r2)
                #pragma unroll
                for (int st = 0; st < 4; ++st)
                    #pragma unroll
                    for (int i = 0; i < 4; ++i) {
                        int row = (rh * 2 + r2) * 16 + q * 4 + i;
                        int s = st * 16 + m;
                        wb[row * 264 + e * 64 + s] =
                            f2bf(tanhf(accC[r2][st][i]) * ssc[row * E_SZ + e]);
                    }
        }
        __syncthreads();

        // ---------------- phase U: uv = w @ U^T + epilogue, two d-halves ----------------
        #pragma unroll
        for (int hf = 0; hf < 2; ++hf) {
            const int dbase = hf * 512 + wv * 64;
            f32x4 accU[4][4];
            #pragma unroll
            for (int rt = 0; rt < 4; ++rt)
                #pragma unroll
                for (int dt = 0; dt < 4; ++dt) accU[rt][dt] = (f32x4){0.f, 0.f, 0.f, 0.f};
            #pragma unroll
            for (int ks = 0; ks < 8; ++ks) {
                bf16x8 a[4];
                #pragma unroll
                for (int rt = 0; rt < 4; ++rt)
                    a[rt] = *(const bf16x8*)(wb + (rt * 16 + m) * 264 + ks * 32 + q * 8);
                #pragma unroll
                for (int dt = 0; dt < 4; ++dt) {
                    bf16x8 b = *(const bf16x8*)(Ub_l + (size_t)(dbase + dt * 16 + m) * NC
                                                + ks * 32 + q * 8);
                    #pragma unroll
                    for (int rt = 0; rt < 4; ++rt)
                        accU[rt][dt] = __builtin_amdgcn_mfma_f32_16x16x32_bf16(
                            a[rt], b, accU[rt][dt], 0, 0, 0);
                }
            }
            #pragma unroll
            for (int rt = 0; rt < 4; ++rt)
                #pragma unroll
                for (int dt = 0; dt < 4; ++dt) {
                    int d = dbase + dt * 16 + m;
                    float bv = bias_l[d];
                    #pragma unroll
                    for (int i = 0; i < 4; ++i) {
                        int row = rt * 16 + q * 4 + i;
                        size_t off = (size_t)(b0 + row) * D_SZ + d;
                        out[off] = fmaf(x[off], accU[rt][dt][i] + bv, xi[off]);
                    }
                }
        }
        __syncthreads();   // out rows visible to this block's next-layer reads
    }
}

extern "C" void kernel_launch(void* const* d_in, const int* in_sizes, int n_in,
                              void* d_out, int out_size, void* d_ws, size_t ws_size,
                              hipStream_t stream) {
    const float* x  = (const float*)d_in[0];
    const float* U  = (const float*)d_in[1];
    const float* V  = (const float*)d_in[2];
    const float* C  = (const float*)d_in[3];
    const float* bi = (const float*)d_in[4];
    const float* G  = (const float*)d_in[5];
    float* out = (float*)d_out;

    short* Vt = (short*)d_ws;                              // L*256*1024 bf16
    short* Ub = Vt + (size_t)L_SZ * NC * D_SZ;             // L*1024*256 bf16
    short* Ct = Ub + (size_t)L_SZ * D_SZ * NC;             // L*4*64*64 bf16

    pack_vt<<<(L_SZ * NC * D_SZ) / 256, 256, 0, stream>>>(V, Vt);
    pack_ub<<<(L_SZ * D_SZ * NC) / 256, 256, 0, stream>>>(U, Ub);
    pack_ct<<<(L_SZ * E_SZ * R_SZ * R_SZ) / 256, 256, 0, stream>>>(C, Ct);

    cross_fused<<<B_SZ / TR, NTHR, 0, stream>>>(x, G, Vt, Ub, Ct, bi, out);
}

// Round 3
// 1509.926 us; speedup vs baseline: 1.3752x; 1.3752x over previous
//
#include <hip/hip_runtime.h>
#include <math.h>

#define B_SZ 32768
#define D_SZ 1024
#define R_SZ 64
#define E_SZ 4
#define L_SZ 3
#define NC   256          // E*R
#define TR   64           // rows per block
#define NTHR 512          // 8 waves

typedef __attribute__((ext_vector_type(8))) short bf16x8;
typedef __attribute__((ext_vector_type(4))) float f32x4;

__device__ __forceinline__ short f2bf(float f) {
    union { float f; unsigned u; } c; c.f = f;
    unsigned r = c.u + 0x7fffu + ((c.u >> 16) & 1u);   // round-to-nearest-even
    return (short)(r >> 16);
}

// Vt[l][c][d] = bf16(V[l][e][d][r]), c = e*64+r   (B-operand for v1: k=d contiguous)
__global__ __launch_bounds__(256) void pack_vt(const float* __restrict__ V,
                                               short* __restrict__ Vt) {
    int idx = blockIdx.x * 256 + threadIdx.x;          // L*256*1024
    int d = idx & 1023;
    int c = (idx >> 10) & 255;
    int l = idx >> 18;
    int e = c >> 6, r = c & 63;
    Vt[idx] = f2bf(V[((size_t)(l * E_SZ + e) * D_SZ + d) * R_SZ + r]);
}
// Ub[l][d][c] = bf16(U[l][e][d][s]), c = e*64+s    (B-operand for uv: k=c contiguous)
__global__ __launch_bounds__(256) void pack_ub(const float* __restrict__ U,
                                               short* __restrict__ Ub) {
    int idx = blockIdx.x * 256 + threadIdx.x;          // L*1024*256
    int c = idx & 255;
    int d = (idx >> 8) & 1023;
    int l = idx >> 18;
    int e = c >> 6, s = c & 63;
    Ub[idx] = f2bf(U[((size_t)(l * E_SZ + e) * D_SZ + d) * R_SZ + s]);
}
// Ct[l][e][s][r] = bf16(C[l][e][r][s])             (B-operand for v2: k=r contiguous)
__global__ __launch_bounds__(256) void pack_ct(const float* __restrict__ C,
                                               short* __restrict__ Ct) {
    int idx = blockIdx.x * 256 + threadIdx.x;          // L*4*64*64
    int r = idx & 63;
    int s = (idx >> 6) & 63;
    int le = idx >> 12;
    Ct[idx] = f2bf(C[((size_t)le * R_SZ + r) * R_SZ + s]);
}

// All three cross layers fused. Row-wise dependency only, so each block loops
// over layers using `out` as its own inter-layer storage (block-local rows).
// Gating is fused into the staging pass (f32, precision-identical).
// launch_bounds min-waves = 2 blocks/CU: LDS (68KB) caps residency at 2 anyway,
// and 2 blocks/CU = 4 waves/SIMD = 128-VGPR budget (accU[4][4] alone needs 64).
__global__ __launch_bounds__(NTHR, 2) void cross_fused(
    const float* __restrict__ x,           // x0 and layer-0 xi
    const float* __restrict__ G,
    const short* __restrict__ Vt, const short* __restrict__ Ub,
    const short* __restrict__ Ct, const float* __restrict__ bias,
    float* out)
{
    __shared__ short xsA[TR * 136];  // xi chunk, bf16, double-buffered (A)
    __shared__ short xsB[TR * 136];  // (B) — distinct arrays: provable no-alias
    __shared__ short wb[TR * 264];   // v1 then w, bf16, row stride 264
    __shared__ float ssc[TR * E_SZ]; // softmax scores

    const int t = threadIdx.x;
    const int b0 = blockIdx.x * TR;
    const int lane = t & 63;
    const int wv = t >> 6;           // wave 0..7
    const int m = lane & 15;         // A-row / B-col / C-col index
    const int q = lane >> 4;         // quad
    const int srow = t >> 3;         // staging: row
    const int sj = t & 7;            // staging: 16-float slice within 128-chunk

    #pragma unroll 1
    for (int l = 0; l < L_SZ; ++l) {
        const float* xi = (l == 0) ? x : out;
        const short* Vt_l = Vt + (size_t)l * NC * D_SZ;
        const short* Ub_l = Ub + (size_t)l * D_SZ * NC;
        const short* Ct_l = Ct + (size_t)l * E_SZ * R_SZ * R_SZ;
        const float* bias_l = bias + (size_t)l * D_SZ;

        // gating partials, accumulated during staging (f32)
        float g0 = 0.f, g1 = 0.f, g2 = 0.f, g3 = 0.f;

        // stage chunk kc (f32 global -> bf16 LDS) + gating partial accumulate
        auto stage = [&](int kc, short* xbuf) {
            const float4* src = (const float4*)(xi + (size_t)(b0 + srow) * D_SZ + kc * 128 + sj * 16);
            const float4* Gp  = (const float4*)(G + kc * 128 + sj * 16);
            short4* dst = (short4*)(xbuf + srow * 136 + sj * 16);
            #pragma unroll
            for (int p = 0; p < 4; ++p) {
                float4 v = src[p];
                float4 a0 = Gp[p];
                float4 a1 = Gp[p + 256];   // G row stride = D_SZ/4 float4
                float4 a2 = Gp[p + 512];
                float4 a3 = Gp[p + 768];
                g0 += v.x * a0.x + v.y * a0.y + v.z * a0.z + v.w * a0.w;
                g1 += v.x * a1.x + v.y * a1.y + v.z * a1.z + v.w * a1.w;
                g2 += v.x * a2.x + v.y * a2.y + v.z * a2.z + v.w * a2.w;
                g3 += v.x * a3.x + v.y * a3.y + v.z * a3.z + v.w * a3.w;
                short4 s;
                s.x = f2bf(v.x); s.y = f2bf(v.y); s.z = f2bf(v.z); s.w = f2bf(v.w);
                dst[p] = s;
            }
        };

        // ---------------- phase V: v1 = tanh(xi @ V), double-buffered ----------------
        f32x4 accV[4][2];
        #pragma unroll
        for (int rt = 0; rt < 4; ++rt)
            #pragma unroll
            for (int ct = 0; ct < 2; ++ct) accV[rt][ct] = (f32x4){0.f, 0.f, 0.f, 0.f};
        const int cbase = wv * 32;

        auto mfmaV = [&](int kc, const short* xbuf) {
            #pragma unroll
            for (int ks = 0; ks < 4; ++ks) {
                bf16x8 a[4];
                #pragma unroll
                for (int rt = 0; rt < 4; ++rt)
                    a[rt] = *(const bf16x8*)(xbuf + (rt * 16 + m) * 136 + ks * 32 + q * 8);
                #pragma unroll
                for (int ct = 0; ct < 2; ++ct) {
                    bf16x8 b = *(const bf16x8*)(Vt_l + (size_t)(cbase + ct * 16 + m) * D_SZ
                                                + kc * 128 + ks * 32 + q * 8);
                    #pragma unroll
                    for (int rt = 0; rt < 4; ++rt)
                        accV[rt][ct] = __builtin_amdgcn_mfma_f32_16x16x32_bf16(
                            a[rt], b, accV[rt][ct], 0, 0, 0);
                }
            }
        };

        stage(0, xsA);
        __syncthreads();
        #pragma unroll 1
        for (int kc2 = 0; kc2 < 4; ++kc2) {
            stage(2 * kc2 + 1, xsB);       // loads in flight while MFMAing xsA
            mfmaV(2 * kc2, xsA);
            __syncthreads();
            if (kc2 < 3) stage(2 * kc2 + 2, xsA);
            mfmaV(2 * kc2 + 1, xsB);
            __syncthreads();
        }

        // gating partials -> xsA overlay (xs dead now); v1 tanh -> wb
        {
            float* gf = (float*)xsA;
            gf[t * 4 + 0] = g0; gf[t * 4 + 1] = g1;
            gf[t * 4 + 2] = g2; gf[t * 4 + 3] = g3;
        }
        #pragma unroll
        for (int rt = 0; rt < 4; ++rt)
            #pragma unroll
            for (int ct = 0; ct < 2; ++ct)
                #pragma unroll
                for (int i = 0; i < 4; ++i) {
                    int row = rt * 16 + q * 4 + i;
                    int c = cbase + ct * 16 + m;
                    wb[row * 264 + c] = f2bf(tanhf(accV[rt][ct][i]));
                }
        __syncthreads();
        if (t < TR) {
            const float* gf = (const float*)xsA;
            float lg[E_SZ];
            #pragma unroll
            for (int e = 0; e < E_SZ; ++e) {
                float s = 0.f;
                #pragma unroll
                for (int jj = 0; jj < 8; ++jj) s += gf[(t * 8 + jj) * 4 + e];
                lg[e] = s;
            }
            float mx = fmaxf(fmaxf(lg[0], lg[1]), fmaxf(lg[2], lg[3]));
            float den = 0.f, ex[E_SZ];
            #pragma unroll
            for (int e = 0; e < E_SZ; ++e) { ex[e] = __expf(lg[e] - mx); den += ex[e]; }
            float inv = 1.f / den;
            #pragma unroll
            for (int e = 0; e < E_SZ; ++e) ssc[t * E_SZ + e] = ex[e] * inv;
        }
        __syncthreads();

        // ---------------- phase C: v2 = tanh(v1 @ C_e), w = v2*score ----------------
        {
            const int e = wv >> 1, rh = wv & 1;       // wave -> (expert, row-half)
            f32x4 accC[2][4];
            #pragma unroll
            for (int r2 = 0; r2 < 2; ++r2)
                #pragma unroll
                for (int st = 0; st < 4; ++st) accC[r2][st] = (f32x4){0.f, 0.f, 0.f, 0.f};
            #pragma unroll
            for (int ks = 0; ks < 2; ++ks) {
                bf16x8 a[2];
                #pragma unroll
                for (int r2 = 0; r2 < 2; ++r2) {
                    int rt = rh * 2 + r2;
                    a[r2] = *(const bf16x8*)(wb + (rt * 16 + m) * 264 + e * 64 + ks * 32 + q * 8);
                }
                #pragma unroll
                for (int st = 0; st < 4; ++st) {
                    bf16x8 b = *(const bf16x8*)(Ct_l + e * 4096 + (st * 16 + m) * 64 + ks * 32 + q * 8);
                    #pragma unroll
                    for (int r2 = 0; r2 < 2; ++r2)
                        accC[r2][st] = __builtin_amdgcn_mfma_f32_16x16x32_bf16(
                            a[r2], b, accC[r2][st], 0, 0, 0);
                }
            }
            #pragma unroll
            for (int r2 = 0; r2 < 2; ++r2)
                #pragma unroll
                for (int st = 0; st < 4; ++st)
                    #pragma unroll
                    for (int i = 0; i < 4; ++i) {
                        int row = (rh * 2 + r2) * 16 + q * 4 + i;
                        int s = st * 16 + m;
                        wb[row * 264 + e * 64 + s] =
                            f2bf(tanhf(accC[r2][st][i]) * ssc[row * E_SZ + e]);
                    }
        }
        __syncthreads();

        // ---------------- phase U: uv = w @ U^T + epilogue, two d-halves ----------------
        #pragma unroll
        for (int hf = 0; hf < 2; ++hf) {
            const int dbase = hf * 512 + wv * 64;
            f32x4 accU[4][4];
            #pragma unroll
            for (int rt = 0; rt < 4; ++rt)
                #pragma unroll
                for (int dt = 0; dt < 4; ++dt) accU[rt][dt] = (f32x4){0.f, 0.f, 0.f, 0.f};
            #pragma unroll
            for (int ks = 0; ks < 8; ++ks) {
                bf16x8 a[4];
                #pragma unroll
                for (int rt = 0; rt < 4; ++rt)
                    a[rt] = *(const bf16x8*)(wb + (rt * 16 + m) * 264 + ks * 32 + q * 8);
                #pragma unroll
                for (int dt = 0; dt < 4; ++dt) {
                    bf16x8 b = *(const bf16x8*)(Ub_l + (size_t)(dbase + dt * 16 + m) * NC
                                                + ks * 32 + q * 8);
                    #pragma unroll
                    for (int rt = 0; rt < 4; ++rt)
                        accU[rt][dt] = __builtin_amdgcn_mfma_f32_16x16x32_bf16(
                            a[rt], b, accU[rt][dt], 0, 0, 0);
                }
            }
            #pragma unroll
            for (int rt = 0; rt < 4; ++rt)
                #pragma unroll
                for (int dt = 0; dt < 4; ++dt) {
                    int d = dbase + dt * 16 + m;
                    float bv = bias_l[d];
                    #pragma unroll
                    for (int i = 0; i < 4; ++i) {
                        int row = rt * 16 + q * 4 + i;
                        size_t off = (size_t)(b0 + row) * D_SZ + d;
                        out[off] = fmaf(x[off], accU[rt][dt][i] + bv, xi[off]);
                    }
                }
        }
        __syncthreads();   // out rows visible to this block's next-layer reads
    }
}

extern "C" void kernel_launch(void* const* d_in, const int* in_sizes, int n_in,
                              void* d_out, int out_size, void* d_ws, size_t ws_size,
                              hipStream_t stream) {
    const float* x  = (const float*)d_in[0];
    const float* U  = (const float*)d_in[1];
    const float* V  = (const float*)d_in[2];
    const float* C  = (const float*)d_in[3];
    const float* bi = (const float*)d_in[4];
    const float* G  = (const float*)d_in[5];
    float* out = (float*)d_out;

    short* Vt = (short*)d_ws;                              // L*256*1024 bf16
    short* Ub = Vt + (size_t)L_SZ * NC * D_SZ;             // L*1024*256 bf16
    short* Ct = Ub + (size_t)L_SZ * D_SZ * NC;             // L*4*64*64 bf16

    pack_vt<<<(L_SZ * NC * D_SZ) / 256, 256, 0, stream>>>(V, Vt);
    pack_ub<<<(L_SZ * D_SZ * NC) / 256, 256, 0, stream>>>(U, Ub);
    pack_ct<<<(L_SZ * E_SZ * R_SZ * R_SZ) / 256, 256, 0, stream>>>(C, Ct);

    cross_fused<<<B_SZ / TR, NTHR, 0, stream>>>(x, G, Vt, Ub, Ct, bi, out);
}

// Round 4
// 1169.954 us; speedup vs baseline: 1.7749x; 1.2906x over previous
//
#include <hip/hip_runtime.h>
#include <math.h>

#define B_SZ 32768
#define D_SZ 1024
#define R_SZ 64
#define E_SZ 4
#define L_SZ 3
#define NC   256          // E*R
#define TR   64           // rows per block
#define NTHR 512          // 8 waves

typedef __attribute__((ext_vector_type(8))) short bf16x8;
typedef __attribute__((ext_vector_type(4))) float f32x4;

__device__ __forceinline__ short f2bf(float f) {
    union { float f; unsigned u; } c; c.f = f;
    unsigned r = c.u + 0x7fffu + ((c.u >> 16) & 1u);   // round-to-nearest-even
    return (short)(r >> 16);
}

// Vt[l][c][d] = bf16(V[l][e][d][r]), c = e*64+r   (B-operand for v1: k=d contiguous)
__global__ __launch_bounds__(256) void pack_vt(const float* __restrict__ V,
                                               short* __restrict__ Vt) {
    int idx = blockIdx.x * 256 + threadIdx.x;          // L*256*1024
    int d = idx & 1023;
    int c = (idx >> 10) & 255;
    int l = idx >> 18;
    int e = c >> 6, r = c & 63;
    Vt[idx] = f2bf(V[((size_t)(l * E_SZ + e) * D_SZ + d) * R_SZ + r]);
}
// Ub[l][d][c] = bf16(U[l][e][d][s]), c = e*64+s    (B-operand for uv: k=c contiguous)
__global__ __launch_bounds__(256) void pack_ub(const float* __restrict__ U,
                                               short* __restrict__ Ub) {
    int idx = blockIdx.x * 256 + threadIdx.x;          // L*1024*256
    int c = idx & 255;
    int d = (idx >> 8) & 1023;
    int l = idx >> 18;
    int e = c >> 6, s = c & 63;
    Ub[idx] = f2bf(U[((size_t)(l * E_SZ + e) * D_SZ + d) * R_SZ + s]);
}
// Ct[l][e][s][r] = bf16(C[l][e][r][s])             (B-operand for v2: k=r contiguous)
__global__ __launch_bounds__(256) void pack_ct(const float* __restrict__ C,
                                               short* __restrict__ Ct) {
    int idx = blockIdx.x * 256 + threadIdx.x;          // L*4*64*64
    int r = idx & 63;
    int s = (idx >> 6) & 63;
    int le = idx >> 12;
    Ct[idx] = f2bf(C[((size_t)le * R_SZ + r) * R_SZ + s]);
}

// All three cross layers fused; block loops over layers using `out` as its own
// inter-layer storage (row-wise dependency only).
// __launch_bounds__(512, 4): 4 waves/SIMD min = 2 blocks/CU for 512-thr blocks
// (2nd arg is waves per EU, NOT blocks/CU). Unified reg budget = 128/wave, so
// phase U runs as 4 d-quarter passes (accU[4][2] = 32 acc floats live) to fit.
__global__ __launch_bounds__(NTHR, 4) void cross_fused(
    const float* __restrict__ x,           // x0 and layer-0 xi
    const float* __restrict__ G,
    const short* __restrict__ Vt, const short* __restrict__ Ub,
    const short* __restrict__ Ct, const float* __restrict__ bias,
    float* out)
{
    __shared__ short xsA[TR * 136];  // xi chunk, bf16, double-buffered (A)
    __shared__ short xsB[TR * 136];  // (B) — distinct arrays: provable no-alias
    __shared__ short wb[TR * 264];   // v1 then w, bf16, row stride 264
    __shared__ float ssc[TR * E_SZ]; // softmax scores

    const int t = threadIdx.x;
    const int b0 = blockIdx.x * TR;
    const int lane = t & 63;
    const int wv = t >> 6;           // wave 0..7
    const int m = lane & 15;         // A-row / B-col / C-col index
    const int q = lane >> 4;         // quad
    const int srow = t >> 3;         // staging: row
    const int sj = t & 7;            // staging: 16-float slice within 128-chunk

    #pragma unroll 1
    for (int l = 0; l < L_SZ; ++l) {
        const float* xi = (l == 0) ? x : out;
        const short* Vt_l = Vt + (size_t)l * NC * D_SZ;
        const short* Ub_l = Ub + (size_t)l * D_SZ * NC;
        const short* Ct_l = Ct + (size_t)l * E_SZ * R_SZ * R_SZ;
        const float* bias_l = bias + (size_t)l * D_SZ;

        // gating partials, accumulated during staging (f32)
        float g0 = 0.f, g1 = 0.f, g2 = 0.f, g3 = 0.f;

        // stage chunk kc (f32 global -> bf16 LDS) + gating partial accumulate
        auto stage = [&](int kc, short* xbuf) {
            const float4* src = (const float4*)(xi + (size_t)(b0 + srow) * D_SZ + kc * 128 + sj * 16);
            const float4* Gp  = (const float4*)(G + kc * 128 + sj * 16);
            short4* dst = (short4*)(xbuf + srow * 136 + sj * 16);
            #pragma unroll
            for (int p = 0; p < 4; ++p) {
                float4 v = src[p];
                float4 a0 = Gp[p];
                float4 a1 = Gp[p + 256];   // G row stride = D_SZ/4 float4
                float4 a2 = Gp[p + 512];
                float4 a3 = Gp[p + 768];
                g0 += v.x * a0.x + v.y * a0.y + v.z * a0.z + v.w * a0.w;
                g1 += v.x * a1.x + v.y * a1.y + v.z * a1.z + v.w * a1.w;
                g2 += v.x * a2.x + v.y * a2.y + v.z * a2.z + v.w * a2.w;
                g3 += v.x * a3.x + v.y * a3.y + v.z * a3.z + v.w * a3.w;
                short4 s;
                s.x = f2bf(v.x); s.y = f2bf(v.y); s.z = f2bf(v.z); s.w = f2bf(v.w);
                dst[p] = s;
            }
        };

        // ---------------- phase V: v1 = tanh(xi @ V), double-buffered ----------------
        f32x4 accV[4][2];
        #pragma unroll
        for (int rt = 0; rt < 4; ++rt)
            #pragma unroll
            for (int ct = 0; ct < 2; ++ct) accV[rt][ct] = (f32x4){0.f, 0.f, 0.f, 0.f};
        const int cbase = wv * 32;

        auto mfmaV = [&](int kc, const short* xbuf) {
            #pragma unroll
            for (int ks = 0; ks < 4; ++ks) {
                bf16x8 a[4];
                #pragma unroll
                for (int rt = 0; rt < 4; ++rt)
                    a[rt] = *(const bf16x8*)(xbuf + (rt * 16 + m) * 136 + ks * 32 + q * 8);
                #pragma unroll
                for (int ct = 0; ct < 2; ++ct) {
                    bf16x8 b = *(const bf16x8*)(Vt_l + (size_t)(cbase + ct * 16 + m) * D_SZ
                                                + kc * 128 + ks * 32 + q * 8);
                    #pragma unroll
                    for (int rt = 0; rt < 4; ++rt)
                        accV[rt][ct] = __builtin_amdgcn_mfma_f32_16x16x32_bf16(
                            a[rt], b, accV[rt][ct], 0, 0, 0);
                }
            }
        };

        stage(0, xsA);
        __syncthreads();
        #pragma unroll 1
        for (int kc2 = 0; kc2 < 4; ++kc2) {
            stage(2 * kc2 + 1, xsB);       // loads in flight while MFMAing xsA
            mfmaV(2 * kc2, xsA);
            __syncthreads();
            if (kc2 < 3) stage(2 * kc2 + 2, xsA);
            mfmaV(2 * kc2 + 1, xsB);
            __syncthreads();
        }

        // gating partials -> xsA overlay (xs dead now); v1 tanh -> wb
        {
            float* gf = (float*)xsA;
            gf[t * 4 + 0] = g0; gf[t * 4 + 1] = g1;
            gf[t * 4 + 2] = g2; gf[t * 4 + 3] = g3;
        }
        #pragma unroll
        for (int rt = 0; rt < 4; ++rt)
            #pragma unroll
            for (int ct = 0; ct < 2; ++ct)
                #pragma unroll
                for (int i = 0; i < 4; ++i) {
                    int row = rt * 16 + q * 4 + i;
                    int c = cbase + ct * 16 + m;
                    wb[row * 264 + c] = f2bf(tanhf(accV[rt][ct][i]));
                }
        __syncthreads();
        if (t < TR) {
            const float* gf = (const float*)xsA;
            float lg[E_SZ];
            #pragma unroll
            for (int e = 0; e < E_SZ; ++e) {
                float s = 0.f;
                #pragma unroll
                for (int jj = 0; jj < 8; ++jj) s += gf[(t * 8 + jj) * 4 + e];
                lg[e] = s;
            }
            float mx = fmaxf(fmaxf(lg[0], lg[1]), fmaxf(lg[2], lg[3]));
            float den = 0.f, ex[E_SZ];
            #pragma unroll
            for (int e = 0; e < E_SZ; ++e) { ex[e] = __expf(lg[e] - mx); den += ex[e]; }
            float inv = 1.f / den;
            #pragma unroll
            for (int e = 0; e < E_SZ; ++e) ssc[t * E_SZ + e] = ex[e] * inv;
        }
        __syncthreads();

        // ---------------- phase C: v2 = tanh(v1 @ C_e), w = v2*score ----------------
        {
            const int e = wv >> 1, rh = wv & 1;       // wave -> (expert, row-half)
            f32x4 accC[2][4];
            #pragma unroll
            for (int r2 = 0; r2 < 2; ++r2)
                #pragma unroll
                for (int st = 0; st < 4; ++st) accC[r2][st] = (f32x4){0.f, 0.f, 0.f, 0.f};
            #pragma unroll
            for (int ks = 0; ks < 2; ++ks) {
                bf16x8 a[2];
                #pragma unroll
                for (int r2 = 0; r2 < 2; ++r2) {
                    int rt = rh * 2 + r2;
                    a[r2] = *(const bf16x8*)(wb + (rt * 16 + m) * 264 + e * 64 + ks * 32 + q * 8);
                }
                #pragma unroll
                for (int st = 0; st < 4; ++st) {
                    bf16x8 b = *(const bf16x8*)(Ct_l + e * 4096 + (st * 16 + m) * 64 + ks * 32 + q * 8);
                    #pragma unroll
                    for (int r2 = 0; r2 < 2; ++r2)
                        accC[r2][st] = __builtin_amdgcn_mfma_f32_16x16x32_bf16(
                            a[r2], b, accC[r2][st], 0, 0, 0);
                }
            }
            #pragma unroll
            for (int r2 = 0; r2 < 2; ++r2)
                #pragma unroll
                for (int st = 0; st < 4; ++st)
                    #pragma unroll
                    for (int i = 0; i < 4; ++i) {
                        int row = (rh * 2 + r2) * 16 + q * 4 + i;
                        int s = st * 16 + m;
                        wb[row * 264 + e * 64 + s] =
                            f2bf(tanhf(accC[r2][st][i]) * ssc[row * E_SZ + e]);
                    }
        }
        __syncthreads();

        // -------- phase U: uv = w @ U^T + epilogue, 4 d-quarter passes --------
        // 32 acc floats live (vs 64) so 2 blocks/CU fit the 128-reg budget.
        #pragma unroll 1
        for (int hq = 0; hq < 4; ++hq) {
            const int dbase = hq * 256 + wv * 32;
            f32x4 accU[4][2];
            #pragma unroll
            for (int rt = 0; rt < 4; ++rt)
                #pragma unroll
                for (int dt = 0; dt < 2; ++dt) accU[rt][dt] = (f32x4){0.f, 0.f, 0.f, 0.f};
            #pragma unroll
            for (int ks = 0; ks < 8; ++ks) {
                bf16x8 a[4];
                #pragma unroll
                for (int rt = 0; rt < 4; ++rt)
                    a[rt] = *(const bf16x8*)(wb + (rt * 16 + m) * 264 + ks * 32 + q * 8);
                #pragma unroll
                for (int dt = 0; dt < 2; ++dt) {
                    bf16x8 b = *(const bf16x8*)(Ub_l + (size_t)(dbase + dt * 16 + m) * NC
                                                + ks * 32 + q * 8);
                    #pragma unroll
                    for (int rt = 0; rt < 4; ++rt)
                        accU[rt][dt] = __builtin_amdgcn_mfma_f32_16x16x32_bf16(
                            a[rt], b, accU[rt][dt], 0, 0, 0);
                }
            }
            if (l == 0) {          // layer 0: xi == x, single load serves both terms
                #pragma unroll
                for (int rt = 0; rt < 4; ++rt)
                    #pragma unroll
                    for (int dt = 0; dt < 2; ++dt) {
                        int d = dbase + dt * 16 + m;
                        float bv = bias_l[d];
                        #pragma unroll
                        for (int i = 0; i < 4; ++i) {
                            int row = rt * 16 + q * 4 + i;
                            size_t off = (size_t)(b0 + row) * D_SZ + d;
                            float xv = x[off];
                            out[off] = fmaf(xv, accU[rt][dt][i] + bv, xv);
                        }
                    }
            } else {
                #pragma unroll
                for (int rt = 0; rt < 4; ++rt)
                    #pragma unroll
                    for (int dt = 0; dt < 2; ++dt) {
                        int d = dbase + dt * 16 + m;
                        float bv = bias_l[d];
                        #pragma unroll
                        for (int i = 0; i < 4; ++i) {
                            int row = rt * 16 + q * 4 + i;
                            size_t off = (size_t)(b0 + row) * D_SZ + d;
                            out[off] = fmaf(x[off], accU[rt][dt][i] + bv, xi[off]);
                        }
                    }
            }
        }
        __syncthreads();   // out rows visible to this block's next-layer reads
    }
}

extern "C" void kernel_launch(void* const* d_in, const int* in_sizes, int n_in,
                              void* d_out, int out_size, void* d_ws, size_t ws_size,
                              hipStream_t stream) {
    const float* x  = (const float*)d_in[0];
    const float* U  = (const float*)d_in[1];
    const float* V  = (const float*)d_in[2];
    const float* C  = (const float*)d_in[3];
    const float* bi = (const float*)d_in[4];
    const float* G  = (const float*)d_in[5];
    float* out = (float*)d_out;

    short* Vt = (short*)d_ws;                              // L*256*1024 bf16
    short* Ub = Vt + (size_t)L_SZ * NC * D_SZ;             // L*1024*256 bf16
    short* Ct = Ub + (size_t)L_SZ * D_SZ * NC;             // L*4*64*64 bf16

    pack_vt<<<(L_SZ * NC * D_SZ) / 256, 256, 0, stream>>>(V, Vt);
    pack_ub<<<(L_SZ * D_SZ * NC) / 256, 256, 0, stream>>>(U, Ub);
    pack_ct<<<(L_SZ * E_SZ * R_SZ * R_SZ) / 256, 256, 0, stream>>>(C, Ct);

    cross_fused<<<B_SZ / TR, NTHR, 0, stream>>>(x, G, Vt, Ub, Ct, bi, out);
}

// Round 5
// 1089.063 us; speedup vs baseline: 1.9067x; 1.0743x over previous
//
#include <hip/hip_runtime.h>
#include <math.h>

#define B_SZ 32768
#define D_SZ 1024
#define R_SZ 64
#define E_SZ 4
#define L_SZ 3
#define NC   256          // E*R
#define TR   64           // rows per block
#define NTHR 512          // 8 waves
#define GC   16           // gating B-columns (4 experts + 12 zero pad)

typedef __attribute__((ext_vector_type(8))) short bf16x8;
typedef __attribute__((ext_vector_type(4))) float f32x4;

__device__ __forceinline__ short f2bf(float f) {
    union { float f; unsigned u; } c; c.f = f;
    unsigned r = c.u + 0x7fffu + ((c.u >> 16) & 1u);   // round-to-nearest-even
    return (short)(r >> 16);
}

// Vt[l][c][d] = bf16(V[l][e][d][r]), c = e*64+r   (B-operand for v1: k=d contiguous)
__global__ __launch_bounds__(256) void pack_vt(const float* __restrict__ V,
                                               short* __restrict__ Vt) {
    int idx = blockIdx.x * 256 + threadIdx.x;          // L*256*1024
    int d = idx & 1023;
    int c = (idx >> 10) & 255;
    int l = idx >> 18;
    int e = c >> 6, r = c & 63;
    Vt[idx] = f2bf(V[((size_t)(l * E_SZ + e) * D_SZ + d) * R_SZ + r]);
}
// Ub[l][d][c] = bf16(U[l][e][d][s]), c = e*64+s    (B-operand for uv: k=c contiguous)
__global__ __launch_bounds__(256) void pack_ub(const float* __restrict__ U,
                                               short* __restrict__ Ub) {
    int idx = blockIdx.x * 256 + threadIdx.x;          // L*1024*256
    int c = idx & 255;
    int d = (idx >> 8) & 1023;
    int l = idx >> 18;
    int e = c >> 6, s = c & 63;
    Ub[idx] = f2bf(U[((size_t)(l * E_SZ + e) * D_SZ + d) * R_SZ + s]);
}
// Ct[l][e][s][r] = bf16(C[l][e][r][s])             (B-operand for v2: k=r contiguous)
__global__ __launch_bounds__(256) void pack_ct(const float* __restrict__ C,
                                               short* __restrict__ Ct) {
    int idx = blockIdx.x * 256 + threadIdx.x;          // L*4*64*64
    int r = idx & 63;
    int s = (idx >> 6) & 63;
    int le = idx >> 12;
    Ct[idx] = f2bf(C[((size_t)le * R_SZ + r) * R_SZ + s]);
}
// Gt[c][d] = bf16(G[c][d]) for c<4, 0 for 4..15   (gating B-operand, Vt layout)
__global__ __launch_bounds__(256) void pack_gt(const float* __restrict__ G,
                                               short* __restrict__ Gt) {
    int idx = blockIdx.x * 256 + threadIdx.x;          // GC*1024
    int d = idx & 1023;
    int c = idx >> 10;
    Gt[idx] = (c < E_SZ) ? f2bf(G[(size_t)c * D_SZ + d]) : (short)0;
}

// All three cross layers fused; block loops over layers using `out` as its own
// inter-layer storage (row-wise dependency only).
// Register budget: flat_work_group_size 512 + waves_per_eu(4) -> 512/4 = 128
// TOTAL unified regs per wave (VGPR+AGPR) -> 2 blocks/CU (LDS 68KB also fits 2).
// Gating runs on the matrix pipe (wave 0, Gt B-columns) so the staging pass is
// a pure copy: peak demand ~110 regs, no spill (R3/R4 spilled at ~150 demand).
__global__ __attribute__((amdgpu_flat_work_group_size(NTHR, NTHR),
                          amdgpu_waves_per_eu(4)))
void cross_fused(
    const float* __restrict__ x,           // x0 and layer-0 xi
    const short* __restrict__ Gt,
    const short* __restrict__ Vt, const short* __restrict__ Ub,
    const short* __restrict__ Ct, const float* __restrict__ bias,
    float* out)
{
    __shared__ short xsA[TR * 136];  // xi chunk, bf16, double-buffered (A)
    __shared__ short xsB[TR * 136];  // (B) — distinct arrays: provable no-alias
    __shared__ short wb[TR * 264];   // v1 then w, bf16, row stride 264
    __shared__ float ssc[TR * E_SZ]; // softmax scores

    const int t = threadIdx.x;
    const int b0 = blockIdx.x * TR;
    const int lane = t & 63;
    const int wv = t >> 6;           // wave 0..7
    const int m = lane & 15;         // A-row / B-col / C-col index
    const int q = lane >> 4;         // quad
    const int srow = t >> 3;         // staging: row
    const int sj = t & 7;            // staging: 16-float slice within 128-chunk

    #pragma unroll 1
    for (int l = 0; l < L_SZ; ++l) {
        const float* xi = (l == 0) ? x : out;
        const short* Vt_l = Vt + (size_t)l * NC * D_SZ;
        const short* Ub_l = Ub + (size_t)l * D_SZ * NC;
        const short* Ct_l = Ct + (size_t)l * E_SZ * R_SZ * R_SZ;
        const float* bias_l = bias + (size_t)l * D_SZ;

        // stage chunk kc: pure f32 global -> bf16 LDS copy (16 live regs)
        auto stage = [&](int kc, short* xbuf) {
            const float4* src = (const float4*)(xi + (size_t)(b0 + srow) * D_SZ + kc * 128 + sj * 16);
            short4* dst = (short4*)(xbuf + srow * 136 + sj * 16);
            #pragma unroll
            for (int p = 0; p < 4; ++p) {
                float4 v = src[p];
                short4 s;
                s.x = f2bf(v.x); s.y = f2bf(v.y); s.z = f2bf(v.z); s.w = f2bf(v.w);
                dst[p] = s;
            }
        };

        // ---------------- phase V: v1 = tanh(xi @ V), double-buffered ----------------
        // wave 0 additionally accumulates gating logits from Gt columns.
        f32x4 accV[4][2];
        f32x4 acc_g[4];
        #pragma unroll
        for (int rt = 0; rt < 4; ++rt) {
            #pragma unroll
            for (int ct = 0; ct < 2; ++ct) accV[rt][ct] = (f32x4){0.f, 0.f, 0.f, 0.f};
            acc_g[rt] = (f32x4){0.f, 0.f, 0.f, 0.f};
        }
        const int cbase = wv * 32;

        auto mfmaV = [&](int kc, const short* xbuf) {
            #pragma unroll
            for (int ks = 0; ks < 4; ++ks) {
                bf16x8 a[4];
                #pragma unroll
                for (int rt = 0; rt < 4; ++rt)
                    a[rt] = *(const bf16x8*)(xbuf + (rt * 16 + m) * 136 + ks * 32 + q * 8);
                #pragma unroll
                for (int ct = 0; ct < 2; ++ct) {
                    bf16x8 b = *(const bf16x8*)(Vt_l + (size_t)(cbase + ct * 16 + m) * D_SZ
                                                + kc * 128 + ks * 32 + q * 8);
                    #pragma unroll
                    for (int rt = 0; rt < 4; ++rt)
                        accV[rt][ct] = __builtin_amdgcn_mfma_f32_16x16x32_bf16(
                            a[rt], b, accV[rt][ct], 0, 0, 0);
                }
                if (wv == 0) {     // wave-uniform branch: gating columns
                    bf16x8 bg = *(const bf16x8*)(Gt + (size_t)m * D_SZ
                                                 + kc * 128 + ks * 32 + q * 8);
                    #pragma unroll
                    for (int rt = 0; rt < 4; ++rt)
                        acc_g[rt] = __builtin_amdgcn_mfma_f32_16x16x32_bf16(
                            a[rt], bg, acc_g[rt], 0, 0, 0);
                }
            }
        };

        stage(0, xsA);
        __syncthreads();
        #pragma unroll 1
        for (int kc2 = 0; kc2 < 4; ++kc2) {
            stage(2 * kc2 + 1, xsB);       // loads in flight while MFMAing xsA
            mfmaV(2 * kc2, xsA);
            __syncthreads();
            if (kc2 < 3) stage(2 * kc2 + 2, xsA);
            mfmaV(2 * kc2 + 1, xsB);
            __syncthreads();
        }

        // wave 0: softmax over experts (C-layout: row=rt*16+q*4+i, expert=m<4).
        // Butterfly over the 4 expert lanes (m^1, m^2 stay within the quad).
        if (wv == 0) {
            #pragma unroll
            for (int rt = 0; rt < 4; ++rt)
                #pragma unroll
                for (int i = 0; i < 4; ++i) {
                    float lg = acc_g[rt][i];
                    float mx = fmaxf(lg, __shfl_xor(lg, 1));
                    mx = fmaxf(mx, __shfl_xor(mx, 2));
                    float ex = __expf(lg - mx);
                    float sm = ex + __shfl_xor(ex, 1);
                    sm += __shfl_xor(sm, 2);
                    if (m < E_SZ) {
                        int row = rt * 16 + q * 4 + i;
                        ssc[row * E_SZ + m] = ex / sm;
                    }
                }
        }
        // v1 tanh -> wb (all waves)
        #pragma unroll
        for (int rt = 0; rt < 4; ++rt)
            #pragma unroll
            for (int ct = 0; ct < 2; ++ct)
                #pragma unroll
                for (int i = 0; i < 4; ++i) {
                    int row = rt * 16 + q * 4 + i;
                    int c = cbase + ct * 16 + m;
                    wb[row * 264 + c] = f2bf(tanhf(accV[rt][ct][i]));
                }
        __syncthreads();

        // ---------------- phase C: v2 = tanh(v1 @ C_e), w = v2*score ----------------
        {
            const int e = wv >> 1, rh = wv & 1;       // wave -> (expert, row-half)
            f32x4 accC[2][4];
            #pragma unroll
            for (int r2 = 0; r2 < 2; ++r2)
                #pragma unroll
                for (int st = 0; st < 4; ++st) accC[r2][st] = (f32x4){0.f, 0.f, 0.f, 0.f};
            #pragma unroll
            for (int ks = 0; ks < 2; ++ks) {
                bf16x8 a[2];
                #pragma unroll
                for (int r2 = 0; r2 < 2; ++r2) {
                    int rt = rh * 2 + r2;
                    a[r2] = *(const bf16x8*)(wb + (rt * 16 + m) * 264 + e * 64 + ks * 32 + q * 8);
                }
                #pragma unroll
                for (int st = 0; st < 4; ++st) {
                    bf16x8 b = *(const bf16x8*)(Ct_l + e * 4096 + (st * 16 + m) * 64 + ks * 32 + q * 8);
                    #pragma unroll
                    for (int r2 = 0; r2 < 2; ++r2)
                        accC[r2][st] = __builtin_amdgcn_mfma_f32_16x16x32_bf16(
                            a[r2], b, accC[r2][st], 0, 0, 0);
                }
            }
            #pragma unroll
            for (int r2 = 0; r2 < 2; ++r2)
                #pragma unroll
                for (int st = 0; st < 4; ++st)
                    #pragma unroll
                    for (int i = 0; i < 4; ++i) {
                        int row = (rh * 2 + r2) * 16 + q * 4 + i;
                        int s = st * 16 + m;
                        wb[row * 264 + e * 64 + s] =
                            f2bf(tanhf(accC[r2][st][i]) * ssc[row * E_SZ + e]);
                    }
        }
        __syncthreads();

        // -------- phase U: uv = w @ U^T + epilogue, 4 d-quarter passes --------
        // 32 acc floats live so total stays under the 128-reg budget.
        #pragma unroll 1
        for (int hq = 0; hq < 4; ++hq) {
            const int dbase = hq * 256 + wv * 32;
            f32x4 accU[4][2];
            #pragma unroll
            for (int rt = 0; rt < 4; ++rt)
                #pragma unroll
                for (int dt = 0; dt < 2; ++dt) accU[rt][dt] = (f32x4){0.f, 0.f, 0.f, 0.f};
            #pragma unroll
            for (int ks = 0; ks < 8; ++ks) {
                bf16x8 a[4];
                #pragma unroll
                for (int rt = 0; rt < 4; ++rt)
                    a[rt] = *(const bf16x8*)(wb + (rt * 16 + m) * 264 + ks * 32 + q * 8);
                #pragma unroll
                for (int dt = 0; dt < 2; ++dt) {
                    bf16x8 b = *(const bf16x8*)(Ub_l + (size_t)(dbase + dt * 16 + m) * NC
                                                + ks * 32 + q * 8);
                    #pragma unroll
                    for (int rt = 0; rt < 4; ++rt)
                        accU[rt][dt] = __builtin_amdgcn_mfma_f32_16x16x32_bf16(
                            a[rt], b, accU[rt][dt], 0, 0, 0);
                }
            }
            if (l == 0) {          // layer 0: xi == x, single load serves both terms
                #pragma unroll
                for (int rt = 0; rt < 4; ++rt)
                    #pragma unroll
                    for (int dt = 0; dt < 2; ++dt) {
                        int d = dbase + dt * 16 + m;
                        float bv = bias_l[d];
                        #pragma unroll
                        for (int i = 0; i < 4; ++i) {
                            int row = rt * 16 + q * 4 + i;
                            size_t off = (size_t)(b0 + row) * D_SZ + d;
                            float xv = x[off];
                            out[off] = fmaf(xv, accU[rt][dt][i] + bv, xv);
                        }
                    }
            } else {
                #pragma unroll
                for (int rt = 0; rt < 4; ++rt)
                    #pragma unroll
                    for (int dt = 0; dt < 2; ++dt) {
                        int d = dbase + dt * 16 + m;
                        float bv = bias_l[d];
                        #pragma unroll
                        for (int i = 0; i < 4; ++i) {
                            int row = rt * 16 + q * 4 + i;
                            size_t off = (size_t)(b0 + row) * D_SZ + d;
                            out[off] = fmaf(x[off], accU[rt][dt][i] + bv, xi[off]);
                        }
                    }
            }
        }
        __syncthreads();   // out rows visible to this block's next-layer reads
    }
}

extern "C" void kernel_launch(void* const* d_in, const int* in_sizes, int n_in,
                              void* d_out, int out_size, void* d_ws, size_t ws_size,
                              hipStream_t stream) {
    const float* x  = (const float*)d_in[0];
    const float* U  = (const float*)d_in[1];
    const float* V  = (const float*)d_in[2];
    const float* C  = (const float*)d_in[3];
    const float* bi = (const float*)d_in[4];
    const float* G  = (const float*)d_in[5];
    float* out = (float*)d_out;

    short* Vt = (short*)d_ws;                              // L*256*1024 bf16
    short* Ub = Vt + (size_t)L_SZ * NC * D_SZ;             // L*1024*256 bf16
    short* Ct = Ub + (size_t)L_SZ * D_SZ * NC;             // L*4*64*64 bf16
    short* Gt = Ct + (size_t)L_SZ * E_SZ * R_SZ * R_SZ;    // 16*1024 bf16

    pack_vt<<<(L_SZ * NC * D_SZ) / 256, 256, 0, stream>>>(V, Vt);
    pack_ub<<<(L_SZ * D_SZ * NC) / 256, 256, 0, stream>>>(U, Ub);
    pack_ct<<<(L_SZ * E_SZ * R_SZ * R_SZ) / 256, 256, 0, stream>>>(C, Ct);
    pack_gt<<<(GC * D_SZ) / 256, 256, 0, stream>>>(G, Gt);

    cross_fused<<<B_SZ / TR, NTHR, 0, stream>>>(x, Gt, Vt, Ub, Ct, bi, out);
}

// Round 7
// 609.990 us; speedup vs baseline: 3.4042x; 1.7854x over previous
//
#include <hip/hip_runtime.h>
#include <math.h>

#define B_SZ 32768
#define D_SZ 1024
#define R_SZ 64
#define E_SZ 4
#define L_SZ 3
#define NC   256          // E*R
#define TR   64           // rows per block
#define NTHR 512          // 8 waves
#define GC   16           // gating B-columns (4 experts + 12 zero pad)

typedef __attribute__((ext_vector_type(8))) short bf16x8;
typedef __attribute__((ext_vector_type(4))) float f32x4;

__device__ __forceinline__ short f2bf(float f) {
    union { float f; unsigned u; } c; c.f = f;
    unsigned r = c.u + 0x7fffu + ((c.u >> 16) & 1u);   // round-to-nearest-even
    return (short)(r >> 16);
}

// One pack kernel for all weights (saves 3 launch overheads).
// Vt[l][c][d] = bf16(V[l][e][d][r]), c=e*64+r      (v1 B-operand, k=d contiguous)
// Ub[l][d][c] = bf16(U[l][e][d][s]), c=e*64+s      (uv B-operand, k=c contiguous)
// Ct[l][e][s][r] = bf16(C[l][e][r][s])             (v2 B-operand, k=r contiguous)
// Gt[c][d]    = bf16(G[c][d]) c<4 else 0           (gating B-operand, Vt layout)
#define T_VT (L_SZ * NC * D_SZ)
#define T_UB (L_SZ * D_SZ * NC)
#define T_CT (L_SZ * E_SZ * R_SZ * R_SZ)
#define T_GT (GC * D_SZ)
__global__ __launch_bounds__(256) void pack_all(
    const float* __restrict__ V, const float* __restrict__ U,
    const float* __restrict__ C, const float* __restrict__ G,
    short* __restrict__ Vt, short* __restrict__ Ub,
    short* __restrict__ Ct, short* __restrict__ Gt) {
    int idx = blockIdx.x * 256 + threadIdx.x;
    if (idx < T_VT) {
        int d = idx & 1023, c = (idx >> 10) & 255, l = idx >> 18;
        int e = c >> 6, r = c & 63;
        Vt[idx] = f2bf(V[((size_t)(l * E_SZ + e) * D_SZ + d) * R_SZ + r]);
    } else if ((idx -= T_VT) < T_UB) {
        int c = idx & 255, d = (idx >> 8) & 1023, l = idx >> 18;
        int e = c >> 6, s = c & 63;
        Ub[idx] = f2bf(U[((size_t)(l * E_SZ + e) * D_SZ + d) * R_SZ + s]);
    } else if ((idx -= T_UB) < T_CT) {
        int r = idx & 63, s = (idx >> 6) & 63, le = idx >> 12;
        Ct[idx] = f2bf(C[((size_t)le * R_SZ + r) * R_SZ + s]);
    } else if ((idx -= T_CT) < T_GT) {
        int d = idx & 1023, c = idx >> 10;
        Gt[idx] = (c < E_SZ) ? f2bf(G[(size_t)c * D_SZ + d]) : (short)0;
    }
}

// All three cross layers fused; block loops over layers using `out` as its own
// inter-layer storage (row-wise dependency only).
// __launch_bounds__(512, 4): 4 waves/EU -> 128 total unified regs/wave ->
// 2 blocks/CU (LDS 68KB also fits 2). Arch-register demand is kept under the
// allocator's arch/acc split by: gating = 4 regs spread over waves 0-3,
// unroll-capped phase-U ks loop, unroll-1 epilogue row loop (R5 spilled
// ~534 MB of scratch writebacks from hoisted-load pressure).
__global__ __launch_bounds__(NTHR, 4) void cross_fused(
    const float* __restrict__ x,           // x0 and layer-0 xi
    const short* __restrict__ Gt,
    const short* __restrict__ Vt, const short* __restrict__ Ub,
    const short* __restrict__ Ct, const float* __restrict__ bias,
    float* out)
{
    __shared__ short xsA[TR * 136];  // xi chunk, bf16, double-buffered (A)
    __shared__ short xsB[TR * 136];  // (B) — distinct arrays: provable no-alias
    __shared__ short wb[TR * 264];   // v1 then w, bf16, row stride 264
    __shared__ float ssc[TR * E_SZ]; // softmax scores

    const int t = threadIdx.x;
    const int b0 = blockIdx.x * TR;
    const int lane = t & 63;
    const int wv = t >> 6;           // wave 0..7
    const int m = lane & 15;         // A-row / B-col / C-col index
    const int q = lane >> 4;         // quad
    const int srow = t >> 3;         // staging: row
    const int sj = t & 7;            // staging: 16-float slice within 128-chunk

    #pragma unroll 1
    for (int l = 0; l < L_SZ; ++l) {
        const float* xi = (l == 0) ? x : out;
        const short* Vt_l = Vt + (size_t)l * NC * D_SZ;
        const short* Ub_l = Ub + (size_t)l * D_SZ * NC;
        const short* Ct_l = Ct + (size_t)l * E_SZ * R_SZ * R_SZ;
        const float* bias_l = bias + (size_t)l * D_SZ;

        // stage chunk kc: pure f32 global -> bf16 LDS copy (16 live regs)
        auto stage = [&](int kc, short* xbuf) {
            const float4* src = (const float4*)(xi + (size_t)(b0 + srow) * D_SZ + kc * 128 + sj * 16);
            short4* dst = (short4*)(xbuf + srow * 136 + sj * 16);
            #pragma unroll
            for (int p = 0; p < 4; ++p) {
                float4 v = src[p];
                short4 s;
                s.x = f2bf(v.x); s.y = f2bf(v.y); s.z = f2bf(v.z); s.w = f2bf(v.w);
                dst[p] = s;
            }
        };

        // ---------------- phase V: v1 = tanh(xi @ V), double-buffered ----------------
        // waves 0-3 each accumulate the gating logit tile for row-tile wv
        // (one f32x4; A-frag via own ds_read so no dynamic reg indexing).
        f32x4 accV[4][2];
        f32x4 acc_gs = (f32x4){0.f, 0.f, 0.f, 0.f};
        #pragma unroll
        for (int rt = 0; rt < 4; ++rt)
            #pragma unroll
            for (int ct = 0; ct < 2; ++ct) accV[rt][ct] = (f32x4){0.f, 0.f, 0.f, 0.f};
        const int cbase = wv * 32;

        auto mfmaV = [&](int kc, const short* xbuf) {
            #pragma unroll
            for (int ks = 0; ks < 4; ++ks) {
                bf16x8 a[4];
                #pragma unroll
                for (int rt = 0; rt < 4; ++rt)
                    a[rt] = *(const bf16x8*)(xbuf + (rt * 16 + m) * 136 + ks * 32 + q * 8);
                #pragma unroll
                for (int ct = 0; ct < 2; ++ct) {
                    bf16x8 b = *(const bf16x8*)(Vt_l + (size_t)(cbase + ct * 16 + m) * D_SZ
                                                + kc * 128 + ks * 32 + q * 8);
                    #pragma unroll
                    for (int rt = 0; rt < 4; ++rt)
                        accV[rt][ct] = __builtin_amdgcn_mfma_f32_16x16x32_bf16(
                            a[rt], b, accV[rt][ct], 0, 0, 0);
                }
                if (wv < 4) {      // wave-uniform branch: gating tile for row-tile wv
                    bf16x8 ag = *(const bf16x8*)(xbuf + (wv * 16 + m) * 136 + ks * 32 + q * 8);
                    bf16x8 bg = *(const bf16x8*)(Gt + (size_t)m * D_SZ
                                                 + kc * 128 + ks * 32 + q * 8);
                    acc_gs = __builtin_amdgcn_mfma_f32_16x16x32_bf16(ag, bg, acc_gs, 0, 0, 0);
                }
            }
        };

        stage(0, xsA);
        __syncthreads();
        #pragma unroll 1
        for (int kc2 = 0; kc2 < 4; ++kc2) {
            stage(2 * kc2 + 1, xsB);       // loads in flight while MFMAing xsA
            mfmaV(2 * kc2, xsA);
            __syncthreads();
            if (kc2 < 3) stage(2 * kc2 + 2, xsA);
            mfmaV(2 * kc2 + 1, xsB);
            __syncthreads();
        }

        // waves 0-3: softmax over experts for row-tile wv.
        // C layout: col = m (expert, pad cols 4-15 are zero), row = wv*16+q*4+i.
        // xor-1/xor-2 butterflies stay inside each 4-lane m-group.
        if (wv < 4) {
            #pragma unroll
            for (int i = 0; i < 4; ++i) {
                float lg = acc_gs[i];
                float mx = fmaxf(lg, __shfl_xor(lg, 1));
                mx = fmaxf(mx, __shfl_xor(mx, 2));
                float ex = __expf(lg - mx);
                float sm = ex + __shfl_xor(ex, 1);
                sm += __shfl_xor(sm, 2);
                if (m < E_SZ) {
                    int row = wv * 16 + q * 4 + i;
                    ssc[row * E_SZ + m] = ex / sm;
                }
            }
        }
        // v1 tanh -> wb (all waves)
        #pragma unroll
        for (int rt = 0; rt < 4; ++rt)
            #pragma unroll
            for (int ct = 0; ct < 2; ++ct)
                #pragma unroll
                for (int i = 0; i < 4; ++i) {
                    int row = rt * 16 + q * 4 + i;
                    int c = cbase + ct * 16 + m;
                    wb[row * 264 + c] = f2bf(tanhf(accV[rt][ct][i]));
                }
        __syncthreads();

        // ---------------- phase C: v2 = tanh(v1 @ C_e), w = v2*score ----------------
        {
            const int e = wv >> 1, rh = wv & 1;       // wave -> (expert, row-half)
            f32x4 accC[2][4];
            #pragma unroll
            for (int r2 = 0; r2 < 2; ++r2)
                #pragma unroll
                for (int st = 0; st < 4; ++st) accC[r2][st] = (f32x4){0.f, 0.f, 0.f, 0.f};
            #pragma unroll
            for (int ks = 0; ks < 2; ++ks) {
                bf16x8 a[2];
                #pragma unroll
                for (int r2 = 0; r2 < 2; ++r2) {
                    int rt = rh * 2 + r2;
                    a[r2] = *(const bf16x8*)(wb + (rt * 16 + m) * 264 + e * 64 + ks * 32 + q * 8);
                }
                #pragma unroll
                for (int st = 0; st < 4; ++st) {
                    bf16x8 b = *(const bf16x8*)(Ct_l + e * 4096 + (st * 16 + m) * 64 + ks * 32 + q * 8);
                    #pragma unroll
                    for (int r2 = 0; r2 < 2; ++r2)
                        accC[r2][st] = __builtin_amdgcn_mfma_f32_16x16x32_bf16(
                            a[r2], b, accC[r2][st], 0, 0, 0);
                }
            }
            #pragma unroll
            for (int r2 = 0; r2 < 2; ++r2)
                #pragma unroll
                for (int st = 0; st < 4; ++st)
                    #pragma unroll
                    for (int i = 0; i < 4; ++i) {
                        int row = (rh * 2 + r2) * 16 + q * 4 + i;
                        int s = st * 16 + m;
                        wb[row * 264 + e * 64 + s] =
                            f2bf(tanhf(accC[r2][st][i]) * ssc[row * E_SZ + e]);
                    }
        }
        __syncthreads();

        // -------- phase U: uv = w @ U^T + epilogue, 4 d-quarter passes --------
        // unroll 2 on ks caps hoisted Ub b-loads (R5 hoisted 16 loads = 64 regs).
        #pragma unroll 1
        for (int hq = 0; hq < 4; ++hq) {
            const int dbase = hq * 256 + wv * 32;
            f32x4 accU[4][2];
            #pragma unroll
            for (int rt = 0; rt < 4; ++rt)
                #pragma unroll
                for (int dt = 0; dt < 2; ++dt) accU[rt][dt] = (f32x4){0.f, 0.f, 0.f, 0.f};
            #pragma unroll 2
            for (int ks = 0; ks < 8; ++ks) {
                bf16x8 a[4];
                #pragma unroll
                for (int rt = 0; rt < 4; ++rt)
                    a[rt] = *(const bf16x8*)(wb + (rt * 16 + m) * 264 + ks * 32 + q * 8);
                #pragma unroll
                for (int dt = 0; dt < 2; ++dt) {
                    bf16x8 b = *(const bf16x8*)(Ub_l + (size_t)(dbase + dt * 16 + m) * NC
                                                + ks * 32 + q * 8);
                    #pragma unroll
                    for (int rt = 0; rt < 4; ++rt)
                        accU[rt][dt] = __builtin_amdgcn_mfma_f32_16x16x32_bf16(
                            a[rt], b, accU[rt][dt], 0, 0, 0);
                }
            }
            // epilogue: unroll 1 on rt caps hoisted x/xi loads to 16
            if (l == 0) {          // layer 0: xi == x, single load serves both terms
                #pragma unroll 1
                for (int rt = 0; rt < 4; ++rt)
                    #pragma unroll
                    for (int dt = 0; dt < 2; ++dt) {
                        int d = dbase + dt * 16 + m;
                        float bv = bias_l[d];
                        #pragma unroll
                        for (int i = 0; i < 4; ++i) {
                            int row = rt * 16 + q * 4 + i;
                            size_t off = (size_t)(b0 + row) * D_SZ + d;
                            float xv = x[off];
                            out[off] = fmaf(xv, accU[rt][dt][i] + bv, xv);
                        }
                    }
            } else {
                #pragma unroll 1
                for (int rt = 0; rt < 4; ++rt)
                    #pragma unroll
                    for (int dt = 0; dt < 2; ++dt) {
                        int d = dbase + dt * 16 + m;
                        float bv = bias_l[d];
                        #pragma unroll
                        for (int i = 0; i < 4; ++i) {
                            int row = rt * 16 + q * 4 + i;
                            size_t off = (size_t)(b0 + row) * D_SZ + d;
                            out[off] = fmaf(x[off], accU[rt][dt][i] + bv, xi[off]);
                        }
                    }
            }
        }
        __syncthreads();   // out rows visible to this block's next-layer reads
    }
}

extern "C" void kernel_launch(void* const* d_in, const int* in_sizes, int n_in,
                              void* d_out, int out_size, void* d_ws, size_t ws_size,
                              hipStream_t stream) {
    const float* x  = (const float*)d_in[0];
    const float* U  = (const float*)d_in[1];
    const float* V  = (const float*)d_in[2];
    const float* C  = (const float*)d_in[3];
    const float* bi = (const float*)d_in[4];
    const float* G  = (const float*)d_in[5];
    float* out = (float*)d_out;

    short* Vt = (short*)d_ws;                              // L*256*1024 bf16
    short* Ub = Vt + (size_t)L_SZ * NC * D_SZ;             // L*1024*256 bf16
    short* Ct = Ub + (size_t)L_SZ * D_SZ * NC;             // L*4*64*64 bf16
    short* Gt = Ct + (size_t)L_SZ * E_SZ * R_SZ * R_SZ;    // 16*1024 bf16

    const int total = T_VT + T_UB + T_CT + T_GT;
    pack_all<<<(total + 255) / 256, 256, 0, stream>>>(V, U, C, G, Vt, Ub, Ct, Gt);

    cross_fused<<<B_SZ / TR, NTHR, 0, stream>>>(x, Gt, Vt, Ub, Ct, bi, out);
}